// Round 3
// baseline (82.850 us; speedup 1.0000x reference)
//
#include <hip/hip_runtime.h>
#include <math.h>

namespace {

constexpr int LDSS = 76;  // float stride per 8x8 block region in LDS (2-way banks max = free)

// Halved DCT cosines: Ki = 0.5*cos(i*pi/16); K0 = sqrt(1/8) = 0.5*cos(4*pi/16).
#define K0f 0.3535533905932738f
#define K1f 0.4903926402016152f
#define K2f 0.4619397662556434f
#define K3f 0.4157348061512726f
#define K5f 0.2777851165098011f
#define K6f 0.1913417161825449f
#define K7f 0.0975451610080642f

// t = D * x  (t[i] = sum_j D[i][j] x[j]) — forward-DCT butterfly, 36 ops vs 64.
__device__ __forceinline__ void fdct8(const float (&x)[8], float (&t)[8]) {
  float s0 = x[0] + x[7], s1 = x[1] + x[6], s2 = x[2] + x[5], s3 = x[3] + x[4];
  float d0 = x[0] - x[7], d1 = x[1] - x[6], d2 = x[2] - x[5], d3 = x[3] - x[4];
  float ss0 = s0 + s3, ss1 = s1 + s2, ds0 = s0 - s3, ds1 = s1 - s2;
  t[0] = K0f * (ss0 + ss1);
  t[4] = K0f * (ss0 - ss1);
  t[2] = fmaf(K2f, ds0, K6f * ds1);
  t[6] = fmaf(K6f, ds0, -K2f * ds1);
  t[1] = fmaf(K1f, d0, fmaf(K3f, d1, fmaf(K5f, d2, K7f * d3)));
  t[3] = fmaf(K3f, d0, fmaf(-K7f, d1, fmaf(-K1f, d2, -K5f * d3)));
  t[5] = fmaf(K5f, d0, fmaf(-K1f, d1, fmaf(K7f, d2, K3f * d3)));
  t[7] = fmaf(K7f, d0, fmaf(-K5f, d1, fmaf(K3f, d2, -K1f * d3)));
}

// t = D^T * x (t[i] = sum_j D[j][i] x[j]) — inverse-DCT butterfly, 36 ops vs 64.
__device__ __forceinline__ void idct8(const float (&x)[8], float (&t)[8]) {
  float ea = K0f * (x[0] + x[4]);
  float eb = K0f * (x[0] - x[4]);
  float ec = fmaf(K2f, x[2], K6f * x[6]);
  float ed = fmaf(K6f, x[2], -K2f * x[6]);
  float e0 = ea + ec, e1 = eb + ed, e2 = eb - ed, e3 = ea - ec;
  float o0 = fmaf(K1f, x[1], fmaf(K3f, x[3], fmaf(K5f, x[5], K7f * x[7])));
  float o1 = fmaf(K3f, x[1], fmaf(-K7f, x[3], fmaf(-K1f, x[5], -K5f * x[7])));
  float o2 = fmaf(K5f, x[1], fmaf(-K1f, x[3], fmaf(K7f, x[5], K3f * x[7])));
  float o3 = fmaf(K7f, x[1], fmaf(-K5f, x[3], fmaf(K3f, x[5], -K1f * x[7])));
  t[0] = e0 + o0; t[1] = e1 + o1; t[2] = e2 + o2; t[3] = e3 + o3;
  t[4] = e3 - o3; t[5] = e2 - o2; t[6] = e1 - o1; t[7] = e0 - o0;
}

// Joint 8x8 transpose of all 3 channels across the 8 lanes sharing each block.
// Single-wave workgroup: __syncthreads lowers to waitcnt only (s_barrier elided).
__device__ __forceinline__ void transpose3(float (&T)[3][8], float* lds, int blk,
                                           int r) {
#pragma unroll
  for (int c = 0; c < 3; ++c) {
    float* lp = lds + (c * 8 + blk) * LDSS;
#pragma unroll
    for (int j = 0; j < 8; ++j) lp[j * 8 + r] = T[c][j];
  }
  __syncthreads();
#pragma unroll
  for (int c = 0; c < 3; ++c) {
    const float* lp = lds + (c * 8 + blk) * LDSS + r * 8;
    float4 v0 = *reinterpret_cast<const float4*>(lp);
    float4 v1 = *reinterpret_cast<const float4*>(lp + 4);
    T[c][0] = v0.x; T[c][1] = v0.y; T[c][2] = v0.z; T[c][3] = v0.w;
    T[c][4] = v1.x; T[c][5] = v1.y; T[c][6] = v1.z; T[c][7] = v1.w;
  }
  __syncthreads();  // WAR guard before next write burst
}

__device__ __forceinline__ void load8(const float* __restrict__ p, float (&a)[8]) {
  float4 v0 = *reinterpret_cast<const float4*>(p);
  float4 v1 = *reinterpret_cast<const float4*>(p + 4);
  a[0] = v0.x; a[1] = v0.y; a[2] = v0.z; a[3] = v0.w;
  a[4] = v1.x; a[5] = v1.y; a[6] = v1.z; a[7] = v1.w;
}

__device__ __forceinline__ void store8(float* __restrict__ p, const float (&a)[8]) {
  float4 v0 = {a[0], a[1], a[2], a[3]};
  float4 v1 = {a[4], a[5], a[6], a[7]};
  *reinterpret_cast<float4*>(p) = v0;
  *reinterpret_cast<float4*>(p + 4) = v1;
}

// Full pipeline for one strip: RGB regs in, RGB regs out (in place).
// qv/qr: clamped quant values and their reciprocals; [0]=Y table, [1]=chroma.
__device__ __forceinline__ void process_strip(float (&R)[8], float (&G)[8],
                                              float (&B)[8],
                                              const float (&qv)[2][8],
                                              const float (&qr)[2][8], float* lds,
                                              int blk, int r) {
  float A[3][8], T[3][8];
  // clip + RGB -> YCbCr
#pragma unroll
  for (int i = 0; i < 8; ++i) {
    float rv = fminf(fmaxf(R[i], 0.0f), 1.0f);
    float gv = fminf(fmaxf(G[i], 0.0f), 1.0f);
    float bv = fminf(fmaxf(B[i], 0.0f), 1.0f);
    A[0][i] = 0.299f * rv + 0.587f * gv + 0.114f * bv;
    A[1][i] = -0.168736f * rv - 0.331264f * gv + 0.5f * bv + 0.5f;
    A[2][i] = 0.5f * rv - 0.418688f * gv - 0.081312f * bv + 0.5f;
  }
  // Forward: coef = D*X*D; lane ends holding coef column r.
#pragma unroll
  for (int c = 0; c < 3; ++c) idct8(A[c], T[c]);  // T = row . D
  transpose3(T, lds, blk, r);
#pragma unroll
  for (int c = 0; c < 3; ++c) fdct8(T[c], A[c]);
  // Soft-round quant: soft_round(x) ~= kc + sigmoid(50*(x-kc-0.5)),
  // kc = clamp(floor(x),-10,9); other 19 sigmoid terms saturate (<3e-11 err).
#pragma unroll
  for (int c = 0; c < 3; ++c) {
    const int ci = (c > 0);
#pragma unroll
    for (int i = 0; i < 8; ++i) {
      float x = A[c][i] * qr[ci][i];
      float kc = floorf(x);
      kc = fmaxf(-10.0f, fminf(9.0f, kc));
      float z = x - kc - 0.5f;
      float e = __builtin_amdgcn_exp2f(-72.13475204444817f * z);  // exp(-50z)
      float sr = kc + __builtin_amdgcn_rcpf(1.0f + e);
      A[c][i] = sr * qv[ci][i];
    }
  }
  // Inverse: rec = D^T*Q*D^T; lane ends holding rec row r.
#pragma unroll
  for (int c = 0; c < 3; ++c) idct8(A[c], T[c]);
  transpose3(T, lds, blk, r);
#pragma unroll
  for (int c = 0; c < 3; ++c) fdct8(T[c], A[c]);
  // YCbCr -> RGB + clip (back into R/G/B)
#pragma unroll
  for (int i = 0; i < 8; ++i) {
    float y2 = A[0][i];
    float cb2 = A[1][i] - 0.5f;
    float cr2 = A[2][i] - 0.5f;
    float r2 = y2 + 1.402f * cr2;
    float g2 = y2 - 0.344136f * cb2 - 0.714136f * cr2;
    float b2 = y2 + 1.772f * cb2;
    R[i] = fminf(fmaxf(r2, 0.0f), 1.0f);
    G[i] = fminf(fmaxf(g2, 0.0f), 1.0f);
    B[i] = fminf(fmaxf(b2, 0.0f), 1.0f);
  }
}

__global__ __launch_bounds__(64) void jpeg_kernel(
    const float* __restrict__ img, const float* __restrict__ qy,
    const float* __restrict__ qc, float* __restrict__ out) {
  __shared__ float lds[3 * 8 * LDSS];  // 7.3 KB, single-wave WG

  const int lane = threadIdx.x;  // 0..63
  const int blk = lane & 7;      // which of the wave's 8 blocks
  const int r = lane >> 3;       // row within the block

  const int t = blockIdx.x;      // 0..2047: two adjacent strips per wave
  const int b = t >> 8;          // batch (256 tasks per batch)
  const int rr = t & 255;
  const int u = rr >> 2;         // block-row, 0..63
  const int p = rr & 3;          // strip-pair, covers strips 2p, 2p+1

  const int row = u * 8 + r;
  const int colA = p * 128 + blk * 8;

  const size_t ims = 512 * 512;
  const float* pA = img + (size_t)b * 3 * ims + (size_t)row * 512 + colA;
  const float* pB = pA + 64;

  // Issue ALL global loads up front: strip B's HBM latency hides under
  // strip A's compute (software pipeline).
  float RA[8], GA[8], BA[8], RB[8], GB[8], BB[8];
  load8(pA, RA);
  load8(pA + ims, GA);
  load8(pA + 2 * ims, BA);
  load8(pB, RB);
  load8(pB + ims, GB);
  load8(pB + 2 * ims, BB);

  // Quant-table columns for this lane (lane's coef column index is r);
  // clamp + reciprocal hoisted out of both strips' quant loops.
  float qv[2][8], qr[2][8];
#pragma unroll
  for (int i = 0; i < 8; ++i) {
    qv[0][i] = fminf(fmaxf(qy[i * 8 + r], 2.0f), 15.0f);
    qv[1][i] = fminf(fmaxf(qc[i * 8 + r], 2.0f), 15.0f);
    qr[0][i] = __builtin_amdgcn_rcpf(qv[0][i]);
    qr[1][i] = __builtin_amdgcn_rcpf(qv[1][i]);
  }

  float* oA = out + (size_t)b * 3 * ims + (size_t)row * 512 + colA;

  process_strip(RA, GA, BA, qv, qr, lds, blk, r);
  store8(oA, RA);
  store8(oA + ims, GA);
  store8(oA + 2 * ims, BA);

  process_strip(RB, GB, BB, qv, qr, lds, blk, r);
  store8(oA + 64, RB);
  store8(oA + 64 + ims, GB);
  store8(oA + 64 + 2 * ims, BB);
}

}  // namespace

extern "C" void kernel_launch(void* const* d_in, const int* in_sizes, int n_in,
                              void* d_out, int out_size, void* d_ws, size_t ws_size,
                              hipStream_t stream) {
  const float* img = (const float*)d_in[0];
  const float* qy = (const float*)d_in[1];
  const float* qc = (const float*)d_in[2];
  float* out = (float*)d_out;
  // 8 batches * 64 block-rows * 4 strip-pairs = 2048 single-wave workgroups
  jpeg_kernel<<<dim3(2048), dim3(64), 0, stream>>>(img, qy, qc, out);
}